// Round 1
// baseline (350.545 us; speedup 1.0000x reference)
//
#include <hip/hip_runtime.h>

// VectorQuantizer: N=131072 rows of D=64, K=1024 codes.
// out[0 .. N*D)   = quantized (straight-through = x + (q - x))
// out[N*D]        = 1.25 * mean((q - x)^2)

constexpr int N_ROWS = 256 * 512;   // 131072
constexpr int D      = 64;
constexpr int K      = 1024;
constexpr int TPB    = 256;
constexpr int RPT    = 2;                        // rows per thread
constexpr int ROWS_PER_BLOCK = TPB * RPT;        // 512
constexpr int NBLK  = N_ROWS / ROWS_PER_BLOCK;   // 256
constexpr int CHUNK = 64;                        // codes staged in LDS per pass

// ---------------------------------------------------------------- esq ------
__global__ void vq_esq_kernel(const float* __restrict__ emb,
                              float* __restrict__ esq) {
  int k = blockIdx.x * blockDim.x + threadIdx.x;
  if (k >= K) return;
  const float4* e4 = reinterpret_cast<const float4*>(emb + (size_t)k * D);
  float s = 0.f;
#pragma unroll
  for (int i = 0; i < D / 4; ++i) {
    float4 v = e4[i];
    s = fmaf(v.x, v.x, s);
    s = fmaf(v.y, v.y, s);
    s = fmaf(v.z, v.z, s);
    s = fmaf(v.w, v.w, s);
  }
  esq[k] = s;
}

// ---------------------------------------------------------------- main -----
__global__ __launch_bounds__(TPB) void vq_main_kernel(
    const float* __restrict__ x, const float* __restrict__ emb,
    const float* __restrict__ esq, float* __restrict__ out,
    float* __restrict__ partial) {
  __shared__ float se[CHUNK * D];   // 16 KB code chunk
  __shared__ float ses[CHUNK];      // esq chunk
  __shared__ float wsum[TPB / 64];

  const int tid = threadIdx.x;
  const size_t r0 = (size_t)blockIdx.x * ROWS_PER_BLOCK + tid;
  const size_t r1 = r0 + TPB;

  // Load this thread's two rows into registers (128 VGPRs).
  float xr0[D], xr1[D];
  {
    const float4* p0 = reinterpret_cast<const float4*>(x + r0 * D);
    const float4* p1 = reinterpret_cast<const float4*>(x + r1 * D);
#pragma unroll
    for (int i = 0; i < D / 4; ++i) {
      float4 a = p0[i];
      xr0[4 * i + 0] = a.x; xr0[4 * i + 1] = a.y;
      xr0[4 * i + 2] = a.z; xr0[4 * i + 3] = a.w;
      float4 b = p1[i];
      xr1[4 * i + 0] = b.x; xr1[4 * i + 1] = b.y;
      xr1[4 * i + 2] = b.z; xr1[4 * i + 3] = b.w;
    }
  }

  // argmin_k ( ||e_k||^2 - 2 x.e_k )   (||x||^2 is constant per row)
  float best0 = 3.4028235e38f, best1 = 3.4028235e38f;
  int bi0 = 0, bi1 = 0;

  for (int c = 0; c < K / CHUNK; ++c) {
    __syncthreads();
    {
      const float4* src =
          reinterpret_cast<const float4*>(emb + (size_t)c * CHUNK * D);
      float4* dst = reinterpret_cast<float4*>(se);
#pragma unroll
      for (int i = 0; i < (CHUNK * D / 4) / TPB; ++i)
        dst[i * TPB + tid] = src[i * TPB + tid];
      if (tid < CHUNK) ses[tid] = esq[c * CHUNK + tid];
    }
    __syncthreads();

#pragma unroll 2
    for (int j = 0; j < CHUNK; ++j) {
      const float4* e4 = reinterpret_cast<const float4*>(se + j * D);
      float d0a = 0.f, d0b = 0.f, d1a = 0.f, d1b = 0.f;
#pragma unroll
      for (int i = 0; i < D / 4; ++i) {
        float4 v = e4[i];   // broadcast LDS read (uniform addr, conflict-free)
        d0a = fmaf(xr0[4 * i + 0], v.x, d0a);
        d0b = fmaf(xr0[4 * i + 1], v.y, d0b);
        d0a = fmaf(xr0[4 * i + 2], v.z, d0a);
        d0b = fmaf(xr0[4 * i + 3], v.w, d0b);
        d1a = fmaf(xr1[4 * i + 0], v.x, d1a);
        d1b = fmaf(xr1[4 * i + 1], v.y, d1b);
        d1a = fmaf(xr1[4 * i + 2], v.z, d1a);
        d1b = fmaf(xr1[4 * i + 3], v.w, d1b);
      }
      float es = ses[j];
      float dist0 = fmaf(-2.f, d0a + d0b, es);
      float dist1 = fmaf(-2.f, d1a + d1b, es);
      int k = c * CHUNK + j;
      if (dist0 < best0) { best0 = dist0; bi0 = k; }  // first-min wins, like argmin
      if (dist1 < best1) { best1 = dist1; bi1 = k; }
    }
  }

  // Gather chosen codes, write straight-through output, accumulate loss terms.
  float lp = 0.f;
  {
    const float4* q4 = reinterpret_cast<const float4*>(emb + (size_t)bi0 * D);
    float4* o4 = reinterpret_cast<float4*>(out + r0 * D);
#pragma unroll
    for (int i = 0; i < D / 4; ++i) {
      float4 q = q4[i];
      float dx, dy, dz, dw;
      dx = q.x - xr0[4 * i + 0]; dy = q.y - xr0[4 * i + 1];
      dz = q.z - xr0[4 * i + 2]; dw = q.w - xr0[4 * i + 3];
      lp = fmaf(dx, dx, lp); lp = fmaf(dy, dy, lp);
      lp = fmaf(dz, dz, lp); lp = fmaf(dw, dw, lp);
      float4 ov;
      ov.x = xr0[4 * i + 0] + dx;  // same rounding as reference's x + sg(q - x)
      ov.y = xr0[4 * i + 1] + dy;
      ov.z = xr0[4 * i + 2] + dz;
      ov.w = xr0[4 * i + 3] + dw;
      o4[i] = ov;
    }
  }
  {
    const float4* q4 = reinterpret_cast<const float4*>(emb + (size_t)bi1 * D);
    float4* o4 = reinterpret_cast<float4*>(out + r1 * D);
#pragma unroll
    for (int i = 0; i < D / 4; ++i) {
      float4 q = q4[i];
      float dx, dy, dz, dw;
      dx = q.x - xr1[4 * i + 0]; dy = q.y - xr1[4 * i + 1];
      dz = q.z - xr1[4 * i + 2]; dw = q.w - xr1[4 * i + 3];
      lp = fmaf(dx, dx, lp); lp = fmaf(dy, dy, lp);
      lp = fmaf(dz, dz, lp); lp = fmaf(dw, dw, lp);
      float4 ov;
      ov.x = xr1[4 * i + 0] + dx;
      ov.y = xr1[4 * i + 1] + dy;
      ov.z = xr1[4 * i + 2] + dz;
      ov.w = xr1[4 * i + 3] + dw;
      o4[i] = ov;
    }
  }

  // Deterministic block reduction of the loss partial.
#pragma unroll
  for (int off = 32; off > 0; off >>= 1) lp += __shfl_down(lp, off);
  if ((tid & 63) == 0) wsum[tid >> 6] = lp;
  __syncthreads();
  if (tid == 0)
    partial[blockIdx.x] = (wsum[0] + wsum[1]) + (wsum[2] + wsum[3]);
}

// ---------------------------------------------------------------- loss -----
__global__ __launch_bounds__(256) void vq_loss_kernel(
    const float* __restrict__ partial, float* __restrict__ out) {
  __shared__ float wsum[4];
  int tid = threadIdx.x;
  float v = partial[tid];   // NBLK == 256 partials, one per thread
#pragma unroll
  for (int off = 32; off > 0; off >>= 1) v += __shfl_down(v, off);
  if ((tid & 63) == 0) wsum[tid >> 6] = v;
  __syncthreads();
  if (tid == 0) {
    float total = (wsum[0] + wsum[1]) + (wsum[2] + wsum[3]);
    // loss = q_latent + 0.25 * e_latent = 1.25 * mean((q-x)^2)
    out[(size_t)N_ROWS * D] = 1.25f * total / (float)((size_t)N_ROWS * D);
  }
}

// ------------------------------------------------------------- launch ------
extern "C" void kernel_launch(void* const* d_in, const int* in_sizes, int n_in,
                              void* d_out, int out_size, void* d_ws,
                              size_t ws_size, hipStream_t stream) {
  const float* x   = (const float*)d_in[0];   // inputs [131072, 64] fp32
  const float* emb = (const float*)d_in[1];   // embeddings [1024, 64] fp32
  float* out = (float*)d_out;                 // [N*D] quantized + [1] loss
  float* esq = (float*)d_ws;                  // [K] ||e||^2
  float* partial = esq + K;                   // [NBLK] loss partials

  vq_esq_kernel<<<K / TPB, TPB, 0, stream>>>(emb, esq);
  vq_main_kernel<<<NBLK, TPB, 0, stream>>>(x, emb, esq, out, partial);
  vq_loss_kernel<<<1, 256, 0, stream>>>(partial, out);
}

// Round 2
// 75.158 us; speedup vs baseline: 4.6641x; 4.6641x over previous
//
#include <hip/hip_runtime.h>

// VectorQuantizer via MFMA: N=131072 rows, D=64, K=1024 codes.
// dist(n,k) = ||e_k||^2 - 2 x_n.e_k  (||x||^2 constant per row, dropped)
// out[0..N*D) = quantized (x + (q-x)), out[N*D] = 1.25*mean((q-x)^2)

typedef __attribute__((ext_vector_type(8))) __bf16 bf16x8;
typedef __attribute__((ext_vector_type(4))) float f32x4;

constexpr int N_ROWS = 256 * 512;   // 131072
constexpr int D      = 64;
constexpr int K      = 1024;
constexpr int TPB    = 256;                      // 4 waves
constexpr int ROWS_PER_BLOCK = 256;              // 64 rows per wave
constexpr int NBLK   = N_ROWS / ROWS_PER_BLOCK;  // 512
constexpr int NTILE  = K / 16;                   // 64 code tiles

// ------------------------------------------------- prep: E->bf16, ||e||^2 --
__global__ __launch_bounds__(256) void vq_prep_kernel(
    const float* __restrict__ emb, __bf16* __restrict__ ebf,
    float* __restrict__ esq) {
  int k = blockIdx.x * 256 + threadIdx.x;
  if (k >= K) return;
  const float4* e4 = (const float4*)(emb + (size_t)k * D);
  bf16x8* dst = (bf16x8*)(ebf + (size_t)k * D);
  float s = 0.f;
#pragma unroll
  for (int g = 0; g < 8; ++g) {
    float4 a = e4[2 * g], b = e4[2 * g + 1];
    s = fmaf(a.x, a.x, s); s = fmaf(a.y, a.y, s);
    s = fmaf(a.z, a.z, s); s = fmaf(a.w, a.w, s);
    s = fmaf(b.x, b.x, s); s = fmaf(b.y, b.y, s);
    s = fmaf(b.z, b.z, s); s = fmaf(b.w, b.w, s);
    bf16x8 v;
    v[0] = (__bf16)a.x; v[1] = (__bf16)a.y; v[2] = (__bf16)a.z; v[3] = (__bf16)a.w;
    v[4] = (__bf16)b.x; v[5] = (__bf16)b.y; v[6] = (__bf16)b.z; v[7] = (__bf16)b.w;
    dst[g] = v;
  }
  esq[k] = s;
}

// ---------------------------------------------------------------- main -----
__global__ __launch_bounds__(TPB) void vq_main_kernel(
    const float* __restrict__ x, const __bf16* __restrict__ ebf,
    const float* __restrict__ esq, const float* __restrict__ emb,
    float* __restrict__ out, float* __restrict__ partial) {
  __shared__ float s_esq[K];              // 4 KB
  __shared__ int   s_bi[ROWS_PER_BLOCK];  // 1 KB
  __shared__ float s_w[TPB / 64];

  const int tid  = threadIdx.x;
  const int wave = tid >> 6, lane = tid & 63;
  const int lrow = lane & 15;   // A-frag row / B-frag col / C col
  const int kseg = lane >> 4;   // k-segment 0..3

  for (int i = tid; i < K; i += TPB) s_esq[i] = esq[i];

  const size_t rbase = (size_t)blockIdx.x * ROWS_PER_BLOCK + (size_t)wave * 64;

  // Load X fragments (fp32, coalesced: wave covers 16 rows x 256B contiguous)
  // and convert to bf16 in-register. A layout: lane holds row=lane&15,
  // k = (lane>>4)*8 + j (8 contiguous).
  bf16x8 xf[4][2];
#pragma unroll
  for (int rg = 0; rg < 4; ++rg) {
    const float* p = x + (rbase + rg * 16 + lrow) * D + kseg * 8;
#pragma unroll
    for (int kf = 0; kf < 2; ++kf) {
      float4 a = ((const float4*)(p + kf * 32))[0];
      float4 b = ((const float4*)(p + kf * 32))[1];
      bf16x8 v;
      v[0] = (__bf16)a.x; v[1] = (__bf16)a.y; v[2] = (__bf16)a.z; v[3] = (__bf16)a.w;
      v[4] = (__bf16)b.x; v[5] = (__bf16)b.y; v[6] = (__bf16)b.z; v[7] = (__bf16)b.w;
      xf[rg][kf] = v;
    }
  }

  float best[4][4];
  int   bidx[4][4];
#pragma unroll
  for (int rg = 0; rg < 4; ++rg)
#pragma unroll
    for (int j = 0; j < 4; ++j) { best[rg][j] = 3.4028235e38f; bidx[rg][j] = 0; }

  __syncthreads();  // s_esq ready

  // B-frag: lane reads E[code0 + lane&15][(lane>>4)*8 .. +8) -- 16B bf16.
  const __bf16* ebase = ebf + (size_t)lrow * D + kseg * 8;

#pragma unroll 2
  for (int t = 0; t < NTILE; ++t) {
    bf16x8 ef0 = *(const bf16x8*)(ebase + (size_t)t * 16 * D);
    bf16x8 ef1 = *(const bf16x8*)(ebase + (size_t)t * 16 * D + 32);
    float es = s_esq[t * 16 + lrow];   // same-address within 16-lane group: broadcast
    const int code = t * 16 + lrow;    // C col = lane&15 = code-within-tile
#pragma unroll
    for (int rg = 0; rg < 4; ++rg) {
      f32x4 acc = {0.f, 0.f, 0.f, 0.f};
      acc = __builtin_amdgcn_mfma_f32_16x16x32_bf16(xf[rg][0], ef0, acc, 0, 0, 0);
      acc = __builtin_amdgcn_mfma_f32_16x16x32_bf16(xf[rg][1], ef1, acc, 0, 0, 0);
#pragma unroll
      for (int j = 0; j < 4; ++j) {
        float dist = fmaf(-2.f, acc[j], es);
        // ascending t + strict < == first-min-wins within this col slot
        if (dist < best[rg][j]) { best[rg][j] = dist; bidx[rg][j] = code; }
      }
    }
  }

  // Cross-col argmin: reduce over the 16 lanes of each k-group (xor 1,2,4,8),
  // tie -> smaller index (matches jnp.argmin first-min semantics).
#pragma unroll
  for (int m = 1; m <= 8; m <<= 1) {
#pragma unroll
    for (int rg = 0; rg < 4; ++rg)
#pragma unroll
      for (int j = 0; j < 4; ++j) {
        float od = __shfl_xor(best[rg][j], m, 64);
        int   oi = __shfl_xor(bidx[rg][j], m, 64);
        bool take = (od < best[rg][j]) ||
                    (od == best[rg][j] && oi < bidx[rg][j]);
        if (take) { best[rg][j] = od; bidx[rg][j] = oi; }
      }
  }

  // C/D row = (lane>>4)*4 + j -> wave-local row rg*16 + kseg*4 + j.
  // Lanes with lrow<4 publish reg j==lrow (static selects, no scratch).
  if (lrow < 4) {
#pragma unroll
    for (int rg = 0; rg < 4; ++rg) {
      int v = (lrow == 0) ? bidx[rg][0] : (lrow == 1) ? bidx[rg][1]
            : (lrow == 2) ? bidx[rg][2] : bidx[rg][3];
      s_bi[wave * 64 + rg * 16 + kseg * 4 + lrow] = v;
    }
  }
  __syncthreads();

  // Epilogue: one row per lane. fp32 x + fp32 emb -> exact loss.
  const size_t r = rbase + lane;
  const int bi = s_bi[wave * 64 + lane];
  const float4* xp = (const float4*)(x + r * D);
  const float4* qp = (const float4*)(emb + (size_t)bi * D);
  float4* op = (float4*)(out + r * D);
  float lp = 0.f;
#pragma unroll
  for (int i = 0; i < D / 4; ++i) {
    float4 xv = xp[i], qv = qp[i];
    float dx = qv.x - xv.x, dy = qv.y - xv.y;
    float dz = qv.z - xv.z, dw = qv.w - xv.w;
    lp = fmaf(dx, dx, lp); lp = fmaf(dy, dy, lp);
    lp = fmaf(dz, dz, lp); lp = fmaf(dw, dw, lp);
    float4 ov;
    ov.x = xv.x + dx; ov.y = xv.y + dy;   // same rounding as x + sg(q-x)
    ov.z = xv.z + dz; ov.w = xv.w + dw;
    op[i] = ov;
  }

#pragma unroll
  for (int off = 32; off > 0; off >>= 1) lp += __shfl_down(lp, off, 64);
  if (lane == 0) s_w[wave] = lp;
  __syncthreads();
  if (tid == 0)
    partial[blockIdx.x] = (s_w[0] + s_w[1]) + (s_w[2] + s_w[3]);
}

// ---------------------------------------------------------------- loss -----
__global__ __launch_bounds__(256) void vq_loss_kernel(
    const float* __restrict__ partial, float* __restrict__ out) {
  __shared__ float wsum[4];
  int tid = threadIdx.x;
  float v = partial[tid] + partial[tid + 256];  // NBLK == 512
#pragma unroll
  for (int off = 32; off > 0; off >>= 1) v += __shfl_down(v, off, 64);
  if ((tid & 63) == 0) wsum[tid >> 6] = v;
  __syncthreads();
  if (tid == 0) {
    float total = (wsum[0] + wsum[1]) + (wsum[2] + wsum[3]);
    out[(size_t)N_ROWS * D] = 1.25f * total / (float)((size_t)N_ROWS * D);
  }
}

// ------------------------------------------------------------- launch ------
extern "C" void kernel_launch(void* const* d_in, const int* in_sizes, int n_in,
                              void* d_out, int out_size, void* d_ws,
                              size_t ws_size, hipStream_t stream) {
  const float* x   = (const float*)d_in[0];   // [131072, 64] fp32
  const float* emb = (const float*)d_in[1];   // [1024, 64] fp32
  float* out = (float*)d_out;

  char* ws = (char*)d_ws;
  float*  esq     = (float*)ws;                  // 4 KB
  float*  partial = (float*)(ws + 4096);         // 2 KB
  __bf16* ebf     = (__bf16*)(ws + 8192);        // 128 KB

  vq_prep_kernel<<<K / 256, 256, 0, stream>>>(emb, ebf, esq);
  vq_main_kernel<<<NBLK, TPB, 0, stream>>>(x, ebf, esq, emb, out, partial);
  vq_loss_kernel<<<1, 256, 0, stream>>>(partial, out);
}